// Round 5
// baseline (8567.886 us; speedup 1.0000x reference)
//
#include <hip/hip_runtime.h>
#include <math.h>

#define SLEN 512
#define BATCH 32
#define IDIM 768
#define HDIM 256
#define NDIM 1024  // 4*HDIM
#define POLL_MAX (1u << 16)

typedef unsigned short u16;
typedef unsigned int u32;
typedef unsigned long long u64;
typedef __attribute__((ext_vector_type(8))) short short8;     // 8 bf16 (MFMA A/B frag)
typedef __attribute__((ext_vector_type(4))) float float4v;    // MFMA C/D frag
typedef __attribute__((ext_vector_type(4))) unsigned short ushort4v;
typedef __attribute__((ext_vector_type(4))) unsigned int uint4v;

__device__ __forceinline__ float bf2f(u16 v) {
    union { u32 u; float f; } c; c.u = ((u32)v) << 16; return c.f;
}
__device__ __forceinline__ u16 f2bf(float f) {
    union { float f; u32 u; } c; c.f = f;
    u32 u = c.u;
    return (u16)((u + 0x7fffu + ((u >> 16) & 1u)) >> 16);
}
__device__ __forceinline__ float sigm(float x) { return 1.f / (1.f + __expf(-x)); }
__device__ __forceinline__ float tanh_f(float x) { return 1.f - 2.f / (__expf(2.f * x) + 1.f); }

struct WPtrs {
    const float *Wi, *Ui, *bi, *Wf, *Uf, *bfp, *Wog, *Uog, *bog, *Wc, *Uc, *bc, *Wd, *bd;
};

// ---------------- kernel 0: weight conversion ----------------
// W4t: bf16 [1024 n][768 k]  (transposed concat Wi,Wf,Wog,Wc) for GEMM B-frags
// U4t: bf16 [5 mat][256 n][256 k]  (transposed: i,f,o,c,Wd) for recurrence B-frags
// b4 : fp32 [1024] concat gate biases
__global__ void convert_kernel(WPtrs p, u16* __restrict__ W4t, u16* __restrict__ U4t,
                               float* __restrict__ b4) {
    const float* Wg[4] = {p.Wi, p.Wf, p.Wog, p.Wc};
    const float* Ug[4] = {p.Ui, p.Uf, p.Uog, p.Uc};
    const float* bg[4] = {p.bi, p.bfp, p.bog, p.bc};
    const int total = NDIM * IDIM + 5 * HDIM * HDIM + NDIM;
    for (int idx = blockIdx.x * blockDim.x + threadIdx.x; idx < total;
         idx += gridDim.x * blockDim.x) {
        int i = idx;
        if (i < NDIM * IDIM) {
            int n = i / IDIM, k = i - n * IDIM;
            W4t[i] = f2bf(Wg[n >> 8][k * HDIM + (n & 255)]);
        } else if ((i -= NDIM * IDIM) < 5 * HDIM * HDIM) {
            int g = i >> 16, rem = i & 65535, n = rem >> 8, k = rem & 255;
            const float* M = (g < 4) ? Ug[g] : p.Wd;
            U4t[i] = f2bf(M[k * HDIM + n]);
        } else {
            i -= 5 * HDIM * HDIM;
            b4[i] = bg[i >> 8][i & 255];
        }
    }
}

// ---------------- kernel 1: G = x @ W4 + b4  (bf16 MFMA, 128x128 tiles) ----------------
__global__ __launch_bounds__(256) void gemm_g_kernel(const float* __restrict__ x,
                                                     const u16* __restrict__ W4t,
                                                     const float* __restrict__ b4,
                                                     u16* __restrict__ G) {
    __shared__ u16 As[128][40];
    __shared__ u16 Bs[128][40];
    const int bn = blockIdx.x;   // 0..7
    const int bm = blockIdx.y;   // 0..127
    const int tid = threadIdx.x;
    const int w = tid >> 6, lane = tid & 63;
    const int wr = w >> 1, wc = w & 1;
    const int l15 = lane & 15, quad = lane >> 4;
    const int m0 = bm * 128, n0 = bn * 128;

    float4v acc[4][4];
#pragma unroll
    for (int a = 0; a < 4; ++a)
#pragma unroll
        for (int b = 0; b < 4; ++b) acc[a][b] = (float4v)(0.f);

    for (int kt = 0; kt < IDIM / 32; ++kt) {
        const int k0 = kt * 32;
#pragma unroll
        for (int i = 0; i < 4; ++i) {
            int idx = tid + 256 * i;
            int r = idx >> 3, seg = idx & 7;
            float4v xv = *(const float4v*)(x + (size_t)(m0 + r) * IDIM + k0 + seg * 4);
            ushort4v t;
            t.x = f2bf(xv.x); t.y = f2bf(xv.y); t.z = f2bf(xv.z); t.w = f2bf(xv.w);
            *(ushort4v*)(&As[r][seg * 4]) = t;
        }
#pragma unroll
        for (int i = 0; i < 2; ++i) {
            int idx = tid + 256 * i;
            int r = idx >> 2, seg = idx & 3;
            uint4v bv = *(const uint4v*)(W4t + (size_t)(n0 + r) * IDIM + k0 + seg * 8);
            *(uint4v*)(&Bs[r][seg * 8]) = bv;
        }
        __syncthreads();
        short8 afr[4], bfr[4];
#pragma unroll
        for (int mt = 0; mt < 4; ++mt) {
            int row = wr * 64 + mt * 16 + l15;
            afr[mt] = *(const short8*)(&As[row][quad * 8]);
        }
#pragma unroll
        for (int nt = 0; nt < 4; ++nt) {
            int col = wc * 64 + nt * 16 + l15;
            bfr[nt] = *(const short8*)(&Bs[col][quad * 8]);
        }
#pragma unroll
        for (int mt = 0; mt < 4; ++mt)
#pragma unroll
            for (int nt = 0; nt < 4; ++nt)
                acc[mt][nt] = __builtin_amdgcn_mfma_f32_16x16x32_bf16(afr[mt], bfr[nt],
                                                                      acc[mt][nt], 0, 0, 0);
        __syncthreads();
    }
#pragma unroll
    for (int mt = 0; mt < 4; ++mt)
#pragma unroll
        for (int nt = 0; nt < 4; ++nt) {
            int gm = m0 + wr * 64 + mt * 16 + quad * 4;
            int gn = n0 + wc * 64 + nt * 16 + l15;
            float bias = b4[gn];
#pragma unroll
            for (int r = 0; r < 4; ++r) {
                G[(size_t)(gm + r) * NDIM + gn] = f2bf(acc[mt][nt][r] + bias);
            }
        }
}

// ---------------- kernel 2: recurrence (MFMA, tagged exchange, selective re-poll) --
// 8 blocks = 2 dirs x 4 hidden-slices(64). 256 threads = 4 waves; wave w owns hidden
// cols [slice*64+w*16, +16) for all 5 matrices; B-frags in VGPRs for all 512 steps.
// Exchange entry (round-0-PROVEN): u64 = {c,h bf16}<<32 | step. Tag travels in the
// same 8B store as the payload -> no ordering assumptions, producers fire-and-forget
// (no drain, no flag). Agent-scope relaxed atomics, COMPILER-managed (inline-asm
// in-flight windows spill garbage -- rounds 3/4 post-mortem).
// Latency cuts vs round 0: (1) the 32 entry loads are issued BEFORE the G prefetch
// so their MALL latency hides under the HBM wait; (2) re-poll reloads ONLY
// tag-mismatched entries (few hundred B) instead of the full 64KB per pass.
// Bounded poll + sticky dead flag: worst case finite visible error, never a hang.
__global__ __launch_bounds__(256, 1) void recur_mfma_kernel(
    const float* __restrict__ times, const float* __restrict__ bd,
    const u16* __restrict__ U4t, const u16* __restrict__ G,
    u64* __restrict__ exch, float* __restrict__ out) {
    __shared__ u16 hL[32 * 264];  // [b][k], pad 264
    __shared__ u16 cL[32 * 264];
    const int d = blockIdx.x >> 2;
    const int slice = blockIdx.x & 3;
    const int tid = threadIdx.x;
    const int w = tid >> 6;
    const int lane = tid & 63;
    const int l15 = lane & 15;
    const int quad = lane >> 4;
    const int j = slice * 64 + w * 16 + l15;  // owned hidden column (C-layout col)
    const float bdec = bd[j];

    // B fragments: B[k][n], lane n=l15, k = q*32 + quad*8 + e  -> U4t[mat][n][k]
    short8 Bf[5][8];
#pragma unroll
    for (int g = 0; g < 5; ++g)
#pragma unroll
        for (int q = 0; q < 8; ++q)
            Bf[g][q] = *(const short8*)(U4t + (g << 16) + (j << 8) + (q << 5) + (quad << 3));

    float creg[2][4], hreg[2][4];
#pragma unroll
    for (int mt = 0; mt < 2; ++mt)
#pragma unroll
        for (int r = 0; r < 4; ++r) { creg[mt][r] = 0.f; hreg[mt][r] = 0.f; }

    bool dead = false;

    for (int s = 0; s < SLEN; ++s) {
        const int sf = d ? (SLEN - 1 - s) : s;              // G source row
        const int tt = d ? (s == 0 ? 0 : SLEN - s) : s;     // tb = [t0, t511..t1]

        // ---- issue all 32 exchange loads FIRST: latency hides under G prefetch ----
        u64 vals[32];
        const u32 want = (u32)(s - 1);
        const u64* pr = exch + ((size_t)((d << 1) | ((s - 1) & 1)) << 13);
        if (s > 0) {
#pragma unroll
            for (int k = 0; k < 32; ++k)
                vals[k] = __hip_atomic_load(&pr[(k << 8) | tid], __ATOMIC_RELAXED,
                                            __HIP_MEMORY_SCOPE_AGENT);
        }

        // ---- G preacts -> acc init, T (independent of exchange) ----
        float4v acc[5][2];
#pragma unroll
        for (int g = 0; g < 4; ++g)
#pragma unroll
            for (int mt = 0; mt < 2; ++mt) {
                const u16* Gp = G + (size_t)((mt * 16 + quad * 4) * SLEN + sf) * NDIM + g * 256 + j;
                float4v a;
#pragma unroll
                for (int r = 0; r < 4; ++r) a[r] = bf2f(Gp[(size_t)r * SLEN * NDIM]);
                acc[g][mt] = a;
            }
        float Tv[2][4];
#pragma unroll
        for (int mt = 0; mt < 2; ++mt)
#pragma unroll
            for (int r = 0; r < 4; ++r) {
                const int b = mt * 16 + quad * 4 + r;
                Tv[mt][r] = 1.f / logf(times[b * SLEN + tt] + 2.718281828459045f);
            }
#pragma unroll
        for (int mt = 0; mt < 2; ++mt) acc[4][mt] = (float4v)(bdec);

        if (s > 0) {
            // ---- selective re-poll: reload only tag-mismatched entries ----
            u32 pend = 0;
#pragma unroll
            for (int k = 0; k < 32; ++k)
                if ((u32)vals[k] != want) pend |= (1u << k);
            if (!dead) {
                u32 it = 0;
                while (__any((int)(pend != 0))) {
#pragma unroll
                    for (int k = 0; k < 32; ++k) {
                        if (pend & (1u << k)) {
                            u64 v = __hip_atomic_load(&pr[(k << 8) | tid], __ATOMIC_RELAXED,
                                                      __HIP_MEMORY_SCOPE_AGENT);
                            if ((u32)v == want) { vals[k] = v; pend &= ~(1u << k); }
                        }
                    }
                    if (++it > POLL_MAX) { dead = true; break; }  // finite, visible
                }
            }
            // ---- stage to LDS (round-0-proven unpack) ----
#pragma unroll
            for (int k = 0; k < 32; ++k) {
                const u32 hi = (u32)(vals[k] >> 32);
                hL[k * 264 + tid] = (u16)(hi & 0xffffu);
                cL[k * 264 + tid] = (u16)(hi >> 16);
            }
            __syncthreads();

            // ---- A fragments from LDS: A[m][k], m=l15, k = q*32 + quad*8 + e ----
            short8 Ah[2][8], Ac[2][8];
#pragma unroll
            for (int mt = 0; mt < 2; ++mt)
#pragma unroll
                for (int q = 0; q < 8; ++q) {
                    const int off = (mt * 16 + l15) * 264 + q * 32 + quad * 8;
                    Ah[mt][q] = *(const short8*)(hL + off);
                    Ac[mt][q] = *(const short8*)(cL + off);
                }
#pragma unroll
            for (int q = 0; q < 8; ++q)
#pragma unroll
                for (int mt = 0; mt < 2; ++mt) {
                    acc[0][mt] = __builtin_amdgcn_mfma_f32_16x16x32_bf16(Ah[mt][q], Bf[0][q], acc[0][mt], 0, 0, 0);
                    acc[1][mt] = __builtin_amdgcn_mfma_f32_16x16x32_bf16(Ah[mt][q], Bf[1][q], acc[1][mt], 0, 0, 0);
                    acc[2][mt] = __builtin_amdgcn_mfma_f32_16x16x32_bf16(Ah[mt][q], Bf[2][q], acc[2][mt], 0, 0, 0);
                    acc[3][mt] = __builtin_amdgcn_mfma_f32_16x16x32_bf16(Ah[mt][q], Bf[3][q], acc[3][mt], 0, 0, 0);
                    acc[4][mt] = __builtin_amdgcn_mfma_f32_16x16x32_bf16(Ac[mt][q], Bf[4][q], acc[4][mt], 0, 0, 0);
                }
        }

        // ---- epilogue + fire-and-forget tagged publish (round-0-proven) ----
        u64* pw = exch + ((size_t)((d << 1) | (s & 1)) << 13);
#pragma unroll
        for (int mt = 0; mt < 2; ++mt)
#pragma unroll
            for (int r = 0; r < 4; ++r) {
                const int b = mt * 16 + quad * 4 + r;
                const float C_ST = tanh_f(acc[4][mt][r]);
                const float cs = creg[mt][r] - C_ST + Tv[mt][r] * C_ST;
                const float ig = sigm(acc[0][mt][r]);
                const float fg = sigm(acc[1][mt][r]);
                const float og = sigm(acc[2][mt][r]);
                const float Cc = sigm(acc[3][mt][r]);
                const float cn = fg * cs + ig * Cc;
                const float hn = og * tanh_f(cn);
                creg[mt][r] = cn;
                hreg[mt][r] = hn;
                const u32 payload = ((u32)f2bf(cn) << 16) | (u32)f2bf(hn);
                const u64 v = ((u64)payload << 32) | (u64)(u32)s;
                __hip_atomic_store(&pw[(b << 8) | j], v, __ATOMIC_RELAXED,
                                   __HIP_MEMORY_SCOPE_AGENT);
                out[((size_t)b * SLEN + s) * 512 + d * 256 + j] = hn;
            }
        __syncthreads();  // protect LDS against next step's staging
    }

    // h_last, c_last
    const size_t base2 = (size_t)BATCH * SLEN * 512;
#pragma unroll
    for (int mt = 0; mt < 2; ++mt)
#pragma unroll
        for (int r = 0; r < 4; ++r) {
            const int b = mt * 16 + quad * 4 + r;
            out[base2 + b * 512 + d * 256 + j] = hreg[mt][r];
            out[base2 + BATCH * 512 + b * 512 + d * 256 + j] = creg[mt][r];
        }
}

extern "C" void kernel_launch(void* const* d_in, const int* in_sizes, int n_in,
                              void* d_out, int out_size, void* d_ws, size_t ws_size,
                              hipStream_t stream) {
    const float* inputs = (const float*)d_in[0];
    const float* times = (const float*)d_in[1];
    WPtrs p;
    p.Wi = (const float*)d_in[2];  p.Ui = (const float*)d_in[3];  p.bi = (const float*)d_in[4];
    p.Wf = (const float*)d_in[5];  p.Uf = (const float*)d_in[6];  p.bfp = (const float*)d_in[7];
    p.Wog = (const float*)d_in[8]; p.Uog = (const float*)d_in[9]; p.bog = (const float*)d_in[10];
    p.Wc = (const float*)d_in[11]; p.Uc = (const float*)d_in[12]; p.bc = (const float*)d_in[13];
    p.Wd = (const float*)d_in[14]; p.bd = (const float*)d_in[15];

    char* ws = (char*)d_ws;
    u16* W4t = (u16*)ws;                   // 1024*768*2   = 1,572,864 B (gemm phase only)
    u16* U4t = (u16*)(ws + 1572864);       // 5*256*256*2  =   655,360 B
    float* b4 = (float*)(ws + 2228224);    // 1024*4       =     4,096 B
    u16* G = (u16*)(ws + 2232320);         // 16384*1024*2 = 33,554,432 B
    // recur-phase exchange aliases the (dead) W4t region:
    // [2 dir][2 par][32 b][256 k] u64 tagged entries = 262,144 B
    u64* exch = (u64*)ws;

    hipLaunchKernelGGL(convert_kernel, dim3(1024), dim3(256), 0, stream, p, W4t, U4t, b4);
    hipLaunchKernelGGL(gemm_g_kernel, dim3(8, 128), dim3(256), 0, stream, inputs, W4t, b4, G);
    hipMemsetAsync(ws, 0xFF, 262144, stream);  // tags -> 0xFFFFFFFF (never a valid step)
    hipLaunchKernelGGL(recur_mfma_kernel, dim3(8), dim3(256), 0, stream, times, p.bd, U4t, G,
                       exch, (float*)d_out);
}

// Round 6
// 6967.329 us; speedup vs baseline: 1.2297x; 1.2297x over previous
//
#include <hip/hip_runtime.h>
#include <math.h>

#define SLEN 512
#define BATCH 32
#define IDIM 768
#define HDIM 256
#define NDIM 1024  // 4*HDIM
#define POLL_MAX (1u << 16)

typedef unsigned short u16;
typedef unsigned int u32;
typedef unsigned long long u64;
typedef __attribute__((ext_vector_type(8))) short short8;     // 8 bf16 (MFMA A/B frag)
typedef __attribute__((ext_vector_type(4))) float float4v;    // MFMA C/D frag
typedef __attribute__((ext_vector_type(4))) unsigned short ushort4v;
typedef __attribute__((ext_vector_type(4))) unsigned int uint4v;

__device__ __forceinline__ float bf2f(u16 v) {
    union { u32 u; float f; } c; c.u = ((u32)v) << 16; return c.f;
}
__device__ __forceinline__ u16 f2bf(float f) {
    union { float f; u32 u; } c; c.f = f;
    u32 u = c.u;
    return (u16)((u + 0x7fffu + ((u >> 16) & 1u)) >> 16);
}
__device__ __forceinline__ float sigm(float x) { return 1.f / (1.f + __expf(-x)); }
__device__ __forceinline__ float tanh_f(float x) { return 1.f - 2.f / (__expf(2.f * x) + 1.f); }

struct WPtrs {
    const float *Wi, *Ui, *bi, *Wf, *Uf, *bfp, *Wog, *Uog, *bog, *Wc, *Uc, *bc, *Wd, *bd;
};

// ---------------- kernel 0: weight conversion ----------------
// W4t: bf16 [1024 n][768 k]  (transposed concat Wi,Wf,Wog,Wc) for GEMM B-frags
// U4t: bf16 [5 mat][256 n][256 k]  (transposed: i,f,o,c,Wd) for recurrence B-frags
// b4 : fp32 [1024] concat gate biases
__global__ void convert_kernel(WPtrs p, u16* __restrict__ W4t, u16* __restrict__ U4t,
                               float* __restrict__ b4) {
    const float* Wg[4] = {p.Wi, p.Wf, p.Wog, p.Wc};
    const float* Ug[4] = {p.Ui, p.Uf, p.Uog, p.Uc};
    const float* bg[4] = {p.bi, p.bfp, p.bog, p.bc};
    const int total = NDIM * IDIM + 5 * HDIM * HDIM + NDIM;
    for (int idx = blockIdx.x * blockDim.x + threadIdx.x; idx < total;
         idx += gridDim.x * blockDim.x) {
        int i = idx;
        if (i < NDIM * IDIM) {
            int n = i / IDIM, k = i - n * IDIM;
            W4t[i] = f2bf(Wg[n >> 8][k * HDIM + (n & 255)]);
        } else if ((i -= NDIM * IDIM) < 5 * HDIM * HDIM) {
            int g = i >> 16, rem = i & 65535, n = rem >> 8, k = rem & 255;
            const float* M = (g < 4) ? Ug[g] : p.Wd;
            U4t[i] = f2bf(M[k * HDIM + n]);
        } else {
            i -= 5 * HDIM * HDIM;
            b4[i] = bg[i >> 8][i & 255];
        }
    }
}

// ---------------- kernel 1: G = x @ W4 + b4  (bf16 MFMA, 128x128 tiles) ----------------
__global__ __launch_bounds__(256) void gemm_g_kernel(const float* __restrict__ x,
                                                     const u16* __restrict__ W4t,
                                                     const float* __restrict__ b4,
                                                     u16* __restrict__ G) {
    __shared__ u16 As[128][40];
    __shared__ u16 Bs[128][40];
    const int bn = blockIdx.x;   // 0..7
    const int bm = blockIdx.y;   // 0..127
    const int tid = threadIdx.x;
    const int w = tid >> 6, lane = tid & 63;
    const int wr = w >> 1, wc = w & 1;
    const int l15 = lane & 15, quad = lane >> 4;
    const int m0 = bm * 128, n0 = bn * 128;

    float4v acc[4][4];
#pragma unroll
    for (int a = 0; a < 4; ++a)
#pragma unroll
        for (int b = 0; b < 4; ++b) acc[a][b] = (float4v)(0.f);

    for (int kt = 0; kt < IDIM / 32; ++kt) {
        const int k0 = kt * 32;
#pragma unroll
        for (int i = 0; i < 4; ++i) {
            int idx = tid + 256 * i;
            int r = idx >> 3, seg = idx & 7;
            float4v xv = *(const float4v*)(x + (size_t)(m0 + r) * IDIM + k0 + seg * 4);
            ushort4v t;
            t.x = f2bf(xv.x); t.y = f2bf(xv.y); t.z = f2bf(xv.z); t.w = f2bf(xv.w);
            *(ushort4v*)(&As[r][seg * 4]) = t;
        }
#pragma unroll
        for (int i = 0; i < 2; ++i) {
            int idx = tid + 256 * i;
            int r = idx >> 2, seg = idx & 3;
            uint4v bv = *(const uint4v*)(W4t + (size_t)(n0 + r) * IDIM + k0 + seg * 8);
            *(uint4v*)(&Bs[r][seg * 8]) = bv;
        }
        __syncthreads();
        short8 afr[4], bfr[4];
#pragma unroll
        for (int mt = 0; mt < 4; ++mt) {
            int row = wr * 64 + mt * 16 + l15;
            afr[mt] = *(const short8*)(&As[row][quad * 8]);
        }
#pragma unroll
        for (int nt = 0; nt < 4; ++nt) {
            int col = wc * 64 + nt * 16 + l15;
            bfr[nt] = *(const short8*)(&Bs[col][quad * 8]);
        }
#pragma unroll
        for (int mt = 0; mt < 4; ++mt)
#pragma unroll
            for (int nt = 0; nt < 4; ++nt)
                acc[mt][nt] = __builtin_amdgcn_mfma_f32_16x16x32_bf16(afr[mt], bfr[nt],
                                                                      acc[mt][nt], 0, 0, 0);
        __syncthreads();
    }
#pragma unroll
    for (int mt = 0; mt < 4; ++mt)
#pragma unroll
        for (int nt = 0; nt < 4; ++nt) {
            int gm = m0 + wr * 64 + mt * 16 + quad * 4;
            int gn = n0 + wc * 64 + nt * 16 + l15;
            float bias = b4[gn];
#pragma unroll
            for (int r = 0; r < 4; ++r) {
                G[(size_t)(gm + r) * NDIM + gn] = f2bf(acc[mt][nt][r] + bias);
            }
        }
}

// ---------------- kernel 2: recurrence (MFMA, half-split, peer exchange) -----------
// 4 blocks = 2 dirs x 2 halves(128 cols). 512 threads = 8 waves; wave w owns cols
// [half*128 + w*16, +16); B-frags in VGPRs for all 512 steps.
// KEY: each block's OWN 128 k-cols go straight to LDS in its epilogue (no global
// round trip); only the peer's 128 cols are exchanged. Exchange entry (round-0-
// PROVEN): u64 = {c,h bf16}<<32 | step -- tag rides with payload, producers fire-
// and-forget, agent-scope relaxed atomics, COMPILER-managed (inline-asm in-flight
// windows spill garbage; selective re-poll serializes -- rounds 3/4/5 post-mortems).
// Peer loads (8/thread) issued BEFORE the G prefetch; checked AFTER the local-half
// MFMAs -- MALL latency hides under HBM loads + 40 MFMAs. Re-poll is BULK (all 8 in
// flight, one wait). Bounded poll + sticky dead: finite visible error, never a hang.
__global__ __launch_bounds__(512, 2) void recur_mfma_kernel(
    const float* __restrict__ times, const float* __restrict__ bd,
    const u16* __restrict__ U4t, const u16* __restrict__ G,
    u64* __restrict__ exch, float* __restrict__ out) {
    __shared__ u16 hL[32 * 264];  // [b][k 0..255], pad 264
    __shared__ u16 cL[32 * 264];
    const int d = blockIdx.x >> 1;
    const int half = blockIdx.x & 1;
    const int tid = threadIdx.x;
    const int w = tid >> 6;       // 0..7
    const int lane = tid & 63;
    const int l15 = lane & 15;
    const int quad = lane >> 4;
    const int jl = w * 16 + l15;          // col within own half (0..127)
    const int j = half * 128 + jl;        // global hidden col
    const float bdec = bd[j];

    // B fragments: B[k][n], lane n=l15, k = q*32 + quad*8 + e  -> U4t[mat][n][k]
    short8 Bf[5][8];
#pragma unroll
    for (int g = 0; g < 5; ++g)
#pragma unroll
        for (int q = 0; q < 8; ++q)
            Bf[g][q] = *(const short8*)(U4t + (g << 16) + (j << 8) + (q << 5) + (quad << 3));

    float creg[2][4], hreg[2][4];
#pragma unroll
    for (int mt = 0; mt < 2; ++mt)
#pragma unroll
        for (int r = 0; r < 4; ++r) { creg[mt][r] = 0.f; hreg[mt][r] = 0.f; }

    bool dead = false;
    const int q0 = half * 4;              // own-half k starts at q0 (local qs q0..q0+3)
    const int rq0 = 4 - half * 4;         // peer-half k starts here
    const int rcol0 = 128 - half * 128;   // peer-half global col base

    for (int s = 0; s < SLEN; ++s) {
        const int sf = d ? (SLEN - 1 - s) : s;              // G source row
        const int tt = d ? (s == 0 ? 0 : SLEN - s) : s;     // tb = [t0, t511..t1]

        // ---- issue 8 peer loads FIRST: MALL latency hides under G prefetch ----
        u64 vals[8];
        const u32 want = (u32)(s - 1);
        // peer's buffer: [d][par][producer_half = 1-half], 4096 u64 each
        const u64* pr = exch + ((size_t)((((d << 1) | ((s - 1) & 1)) << 1) | (1 - half)) << 12);
        if (s > 0) {
#pragma unroll
            for (int k = 0; k < 8; ++k)
                vals[k] = __hip_atomic_load(&pr[(k << 9) | tid], __ATOMIC_RELAXED,
                                            __HIP_MEMORY_SCOPE_AGENT);
        }

        // ---- G preacts -> acc init, T (independent of exchange) ----
        float4v acc[5][2];
#pragma unroll
        for (int g = 0; g < 4; ++g)
#pragma unroll
            for (int mt = 0; mt < 2; ++mt) {
                const u16* Gp = G + (size_t)((mt * 16 + quad * 4) * SLEN + sf) * NDIM + g * 256 + j;
                float4v a;
#pragma unroll
                for (int r = 0; r < 4; ++r) a[r] = bf2f(Gp[(size_t)r * SLEN * NDIM]);
                acc[g][mt] = a;
            }
        float Tv[2][4];
#pragma unroll
        for (int mt = 0; mt < 2; ++mt)
#pragma unroll
            for (int r = 0; r < 4; ++r) {
                const int b = mt * 16 + quad * 4 + r;
                Tv[mt][r] = 1.f / logf(times[b * SLEN + tt] + 2.718281828459045f);
            }
#pragma unroll
        for (int mt = 0; mt < 2; ++mt) acc[4][mt] = (float4v)(bdec);

        if (s > 0) {
            // ---- local-half MFMAs (own 128 k-cols, staged via LDS last step) ----
            {
                short8 Ah[2][4], Ac[2][4];
#pragma unroll
                for (int mt = 0; mt < 2; ++mt)
#pragma unroll
                    for (int ql = 0; ql < 4; ++ql) {
                        const int off = (mt * 16 + l15) * 264 + (q0 + ql) * 32 + quad * 8;
                        Ah[mt][ql] = *(const short8*)(hL + off);
                        Ac[mt][ql] = *(const short8*)(cL + off);
                    }
#pragma unroll
                for (int ql = 0; ql < 4; ++ql)
#pragma unroll
                    for (int mt = 0; mt < 2; ++mt) {
                        acc[0][mt] = __builtin_amdgcn_mfma_f32_16x16x32_bf16(Ah[mt][ql], Bf[0][q0 + ql], acc[0][mt], 0, 0, 0);
                        acc[1][mt] = __builtin_amdgcn_mfma_f32_16x16x32_bf16(Ah[mt][ql], Bf[1][q0 + ql], acc[1][mt], 0, 0, 0);
                        acc[2][mt] = __builtin_amdgcn_mfma_f32_16x16x32_bf16(Ah[mt][ql], Bf[2][q0 + ql], acc[2][mt], 0, 0, 0);
                        acc[3][mt] = __builtin_amdgcn_mfma_f32_16x16x32_bf16(Ah[mt][ql], Bf[3][q0 + ql], acc[3][mt], 0, 0, 0);
                        acc[4][mt] = __builtin_amdgcn_mfma_f32_16x16x32_bf16(Ac[mt][ql], Bf[4][q0 + ql], acc[4][mt], 0, 0, 0);
                    }
            }
            // ---- peer poll: check tags; BULK re-read on miss (bounded, sticky) ----
            if (!dead) {
                u32 it = 0;
                for (;;) {
                    int ok = 1;
#pragma unroll
                    for (int k = 0; k < 8; ++k) ok &= ((u32)vals[k] == want);
                    if (__all(ok)) break;
                    if (++it > POLL_MAX) { dead = true; break; }  // finite, visible
#pragma unroll
                    for (int k = 0; k < 8; ++k)
                        vals[k] = __hip_atomic_load(&pr[(k << 9) | tid], __ATOMIC_RELAXED,
                                                    __HIP_MEMORY_SCOPE_AGENT);
                }
            }
            // ---- unpack peer -> LDS remote half ----
            const int rcol = rcol0 + (tid & 127);
            const int rb0 = tid >> 7;  // 0..3
#pragma unroll
            for (int k = 0; k < 8; ++k) {
                const int b = (k << 2) | rb0;
                const u32 hi = (u32)(vals[k] >> 32);
                hL[b * 264 + rcol] = (u16)(hi & 0xffffu);
                cL[b * 264 + rcol] = (u16)(hi >> 16);
            }
        }
        __syncthreads();  // B1: remote half staged; own-half reads (above) complete

        if (s > 0) {
            // ---- remote-half MFMAs ----
            short8 Ah[2][4], Ac[2][4];
#pragma unroll
            for (int mt = 0; mt < 2; ++mt)
#pragma unroll
                for (int ql = 0; ql < 4; ++ql) {
                    const int off = (mt * 16 + l15) * 264 + (rq0 + ql) * 32 + quad * 8;
                    Ah[mt][ql] = *(const short8*)(hL + off);
                    Ac[mt][ql] = *(const short8*)(cL + off);
                }
#pragma unroll
            for (int ql = 0; ql < 4; ++ql)
#pragma unroll
                for (int mt = 0; mt < 2; ++mt) {
                    acc[0][mt] = __builtin_amdgcn_mfma_f32_16x16x32_bf16(Ah[mt][ql], Bf[0][rq0 + ql], acc[0][mt], 0, 0, 0);
                    acc[1][mt] = __builtin_amdgcn_mfma_f32_16x16x32_bf16(Ah[mt][ql], Bf[1][rq0 + ql], acc[1][mt], 0, 0, 0);
                    acc[2][mt] = __builtin_amdgcn_mfma_f32_16x16x32_bf16(Ah[mt][ql], Bf[2][rq0 + ql], acc[2][mt], 0, 0, 0);
                    acc[3][mt] = __builtin_amdgcn_mfma_f32_16x16x32_bf16(Ah[mt][ql], Bf[3][rq0 + ql], acc[3][mt], 0, 0, 0);
                    acc[4][mt] = __builtin_amdgcn_mfma_f32_16x16x32_bf16(Ac[mt][ql], Bf[4][rq0 + ql], acc[4][mt], 0, 0, 0);
                }
        }

        // ---- epilogue: gates; publish peer entries FIRST, then LDS, then out ----
        u64* pw = exch + ((size_t)((((d << 1) | (s & 1)) << 1) | half) << 12);
        float hv[2][4];
#pragma unroll
        for (int mt = 0; mt < 2; ++mt)
#pragma unroll
            for (int r = 0; r < 4; ++r) {
                const int b = mt * 16 + quad * 4 + r;
                const float C_ST = tanh_f(acc[4][mt][r]);
                const float cs = creg[mt][r] - C_ST + Tv[mt][r] * C_ST;
                const float ig = sigm(acc[0][mt][r]);
                const float fg = sigm(acc[1][mt][r]);
                const float og = sigm(acc[2][mt][r]);
                const float Cc = sigm(acc[3][mt][r]);
                const float cn = fg * cs + ig * Cc;
                const float hn = og * tanh_f(cn);
                creg[mt][r] = cn;
                hreg[mt][r] = hn;
                hv[mt][r] = hn;
                const u32 payload = ((u32)f2bf(cn) << 16) | (u32)f2bf(hn);
                const u64 v = ((u64)payload << 32) | (u64)(u32)s;
                __hip_atomic_store(&pw[(b << 7) | jl], v, __ATOMIC_RELAXED,
                                   __HIP_MEMORY_SCOPE_AGENT);
            }
        // own half -> LDS for next step's local phase (same f2bf rounding as peer path)
#pragma unroll
        for (int mt = 0; mt < 2; ++mt)
#pragma unroll
            for (int r = 0; r < 4; ++r) {
                const int b = mt * 16 + quad * 4 + r;
                hL[b * 264 + j] = f2bf(hreg[mt][r]);
                cL[b * 264 + j] = f2bf(creg[mt][r]);
            }
#pragma unroll
        for (int mt = 0; mt < 2; ++mt)
#pragma unroll
            for (int r = 0; r < 4; ++r) {
                const int b = mt * 16 + quad * 4 + r;
                out[((size_t)b * SLEN + s) * 512 + d * 256 + j] = hv[mt][r];
            }
        __syncthreads();  // B2: LDS writes visible before next step's local reads
    }

    // h_last, c_last
    const size_t base2 = (size_t)BATCH * SLEN * 512;
#pragma unroll
    for (int mt = 0; mt < 2; ++mt)
#pragma unroll
        for (int r = 0; r < 4; ++r) {
            const int b = mt * 16 + quad * 4 + r;
            out[base2 + b * 512 + d * 256 + j] = hreg[mt][r];
            out[base2 + BATCH * 512 + b * 512 + d * 256 + j] = creg[mt][r];
        }
}

extern "C" void kernel_launch(void* const* d_in, const int* in_sizes, int n_in,
                              void* d_out, int out_size, void* d_ws, size_t ws_size,
                              hipStream_t stream) {
    const float* inputs = (const float*)d_in[0];
    const float* times = (const float*)d_in[1];
    WPtrs p;
    p.Wi = (const float*)d_in[2];  p.Ui = (const float*)d_in[3];  p.bi = (const float*)d_in[4];
    p.Wf = (const float*)d_in[5];  p.Uf = (const float*)d_in[6];  p.bfp = (const float*)d_in[7];
    p.Wog = (const float*)d_in[8]; p.Uog = (const float*)d_in[9]; p.bog = (const float*)d_in[10];
    p.Wc = (const float*)d_in[11]; p.Uc = (const float*)d_in[12]; p.bc = (const float*)d_in[13];
    p.Wd = (const float*)d_in[14]; p.bd = (const float*)d_in[15];

    char* ws = (char*)d_ws;
    u16* W4t = (u16*)ws;                   // 1024*768*2   = 1,572,864 B (gemm phase only)
    u16* U4t = (u16*)(ws + 1572864);       // 5*256*256*2  =   655,360 B
    float* b4 = (float*)(ws + 2228224);    // 1024*4       =     4,096 B
    u16* G = (u16*)(ws + 2232320);         // 16384*1024*2 = 33,554,432 B
    // recur-phase exchange aliases the (dead) W4t region:
    // [2 dir][2 par][2 producer-half][32 b][128 col] u64 tagged entries = 262,144 B
    u64* exch = (u64*)ws;

    hipLaunchKernelGGL(convert_kernel, dim3(1024), dim3(256), 0, stream, p, W4t, U4t, b4);
    hipLaunchKernelGGL(gemm_g_kernel, dim3(8, 128), dim3(256), 0, stream, inputs, W4t, b4, G);
    hipMemsetAsync(ws, 0xFF, 262144, stream);  // tags -> 0xFFFFFFFF (never a valid step)
    hipLaunchKernelGGL(recur_mfma_kernel, dim3(4), dim3(512), 0, stream, times, p.bd, U4t, G,
                       exch, (float*)d_out);
}

// Round 7
// 5262.327 us; speedup vs baseline: 1.6282x; 1.3240x over previous
//
#include <hip/hip_runtime.h>
#include <math.h>

#define SLEN 512
#define BATCH 32
#define IDIM 768
#define HDIM 256
#define NDIM 1024  // 4*HDIM
#define POLL_MAX (1u << 16)

typedef unsigned short u16;
typedef unsigned int u32;
typedef unsigned long long u64;
typedef __attribute__((ext_vector_type(8))) short short8;     // 8 bf16 (MFMA A/B frag)
typedef __attribute__((ext_vector_type(4))) float float4v;    // MFMA C/D frag
typedef __attribute__((ext_vector_type(4))) unsigned short ushort4v;
typedef __attribute__((ext_vector_type(4))) unsigned int uint4v;

__device__ __forceinline__ float bf2f(u16 v) {
    union { u32 u; float f; } c; c.u = ((u32)v) << 16; return c.f;
}
__device__ __forceinline__ u16 f2bf(float f) {
    union { float f; u32 u; } c; c.f = f;
    u32 u = c.u;
    return (u16)((u + 0x7fffu + ((u >> 16) & 1u)) >> 16);
}
__device__ __forceinline__ float sigm(float x) { return 1.f / (1.f + __expf(-x)); }
__device__ __forceinline__ float tanh_f(float x) { return 1.f - 2.f / (__expf(2.f * x) + 1.f); }

struct WPtrs {
    const float *Wi, *Ui, *bi, *Wf, *Uf, *bfp, *Wog, *Uog, *bog, *Wc, *Uc, *bc, *Wd, *bd;
};

// ---------------- kernel 0: weight conversion ----------------
// W4t: bf16 [1024 n][768 k]  (transposed concat Wi,Wf,Wog,Wc) for GEMM B-frags
// U4t: bf16 [5 mat][256 n][256 k]  (transposed: i,f,o,c,Wd) for recurrence B-frags
// b4 : fp32 [1024] concat gate biases
__global__ void convert_kernel(WPtrs p, u16* __restrict__ W4t, u16* __restrict__ U4t,
                               float* __restrict__ b4) {
    const float* Wg[4] = {p.Wi, p.Wf, p.Wog, p.Wc};
    const float* Ug[4] = {p.Ui, p.Uf, p.Uog, p.Uc};
    const float* bg[4] = {p.bi, p.bfp, p.bog, p.bc};
    const int total = NDIM * IDIM + 5 * HDIM * HDIM + NDIM;
    for (int idx = blockIdx.x * blockDim.x + threadIdx.x; idx < total;
         idx += gridDim.x * blockDim.x) {
        int i = idx;
        if (i < NDIM * IDIM) {
            int n = i / IDIM, k = i - n * IDIM;
            W4t[i] = f2bf(Wg[n >> 8][k * HDIM + (n & 255)]);
        } else if ((i -= NDIM * IDIM) < 5 * HDIM * HDIM) {
            int g = i >> 16, rem = i & 65535, n = rem >> 8, k = rem & 255;
            const float* M = (g < 4) ? Ug[g] : p.Wd;
            U4t[i] = f2bf(M[k * HDIM + n]);
        } else {
            i -= 5 * HDIM * HDIM;
            b4[i] = bg[i >> 8][i & 255];
        }
    }
}

// ---------------- kernel 1: G = x @ W4 + b4  (bf16 MFMA, 128x128 tiles) ----------------
__global__ __launch_bounds__(256) void gemm_g_kernel(const float* __restrict__ x,
                                                     const u16* __restrict__ W4t,
                                                     const float* __restrict__ b4,
                                                     u16* __restrict__ G) {
    __shared__ u16 As[128][40];
    __shared__ u16 Bs[128][40];
    const int bn = blockIdx.x;   // 0..7
    const int bm = blockIdx.y;   // 0..127
    const int tid = threadIdx.x;
    const int w = tid >> 6, lane = tid & 63;
    const int wr = w >> 1, wc = w & 1;
    const int l15 = lane & 15, quad = lane >> 4;
    const int m0 = bm * 128, n0 = bn * 128;

    float4v acc[4][4];
#pragma unroll
    for (int a = 0; a < 4; ++a)
#pragma unroll
        for (int b = 0; b < 4; ++b) acc[a][b] = (float4v)(0.f);

    for (int kt = 0; kt < IDIM / 32; ++kt) {
        const int k0 = kt * 32;
#pragma unroll
        for (int i = 0; i < 4; ++i) {
            int idx = tid + 256 * i;
            int r = idx >> 3, seg = idx & 7;
            float4v xv = *(const float4v*)(x + (size_t)(m0 + r) * IDIM + k0 + seg * 4);
            ushort4v t;
            t.x = f2bf(xv.x); t.y = f2bf(xv.y); t.z = f2bf(xv.z); t.w = f2bf(xv.w);
            *(ushort4v*)(&As[r][seg * 4]) = t;
        }
#pragma unroll
        for (int i = 0; i < 2; ++i) {
            int idx = tid + 256 * i;
            int r = idx >> 2, seg = idx & 3;
            uint4v bv = *(const uint4v*)(W4t + (size_t)(n0 + r) * IDIM + k0 + seg * 8);
            *(uint4v*)(&Bs[r][seg * 8]) = bv;
        }
        __syncthreads();
        short8 afr[4], bfr[4];
#pragma unroll
        for (int mt = 0; mt < 4; ++mt) {
            int row = wr * 64 + mt * 16 + l15;
            afr[mt] = *(const short8*)(&As[row][quad * 8]);
        }
#pragma unroll
        for (int nt = 0; nt < 4; ++nt) {
            int col = wc * 64 + nt * 16 + l15;
            bfr[nt] = *(const short8*)(&Bs[col][quad * 8]);
        }
#pragma unroll
        for (int mt = 0; mt < 4; ++mt)
#pragma unroll
            for (int nt = 0; nt < 4; ++nt)
                acc[mt][nt] = __builtin_amdgcn_mfma_f32_16x16x32_bf16(afr[mt], bfr[nt],
                                                                      acc[mt][nt], 0, 0, 0);
        __syncthreads();
    }
#pragma unroll
    for (int mt = 0; mt < 4; ++mt)
#pragma unroll
        for (int nt = 0; nt < 4; ++nt) {
            int gm = m0 + wr * 64 + mt * 16 + quad * 4;
            int gn = n0 + wc * 64 + nt * 16 + l15;
            float bias = b4[gn];
#pragma unroll
            for (int r = 0; r < 4; ++r) {
                G[(size_t)(gm + r) * NDIM + gn] = f2bf(acc[mt][nt][r] + bias);
            }
        }
}

// ---------------- kernel 2: recurrence (MFMA, half-split, peer exchange) -----------
// 4 blocks = 2 dirs x 2 halves(128 cols). 512 threads = 8 waves; wave w owns cols
// [half*128 + w*16, +16); B-frags in VGPRs for all 512 steps.
// Round-6 post-mortem fix: Bf was runtime-indexed (q0 = half*4) -> rule #20 ->
// entire Bf demoted to scratch (VGPR_Count=112, ~13us/step of private-mem traffic).
// Now Bf[g][i] is loaded from k-slice q=(half*4+i)&7 so local phase = Bf[g][0..3],
// remote phase = Bf[g][4..7] -- ALL literal register indices; LDS addresses keep the
// runtime q0/rq0 (plain address math). Same math as the verified round-6 kernel.
// Exchange (round-0-proven): u64 = {c,h bf16}<<32 | step; tag rides with payload,
// fire-and-forget agent-scope relaxed atomics, compiler-managed. Peer loads issued
// BEFORE the G prefetch; checked AFTER local-half MFMAs; bulk re-poll; bounded +
// sticky dead (finite visible error, never a hang).
__global__ __launch_bounds__(512, 2) void recur_mfma_kernel(
    const float* __restrict__ times, const float* __restrict__ bd,
    const u16* __restrict__ U4t, const u16* __restrict__ G,
    u64* __restrict__ exch, float* __restrict__ out) {
    __shared__ u16 hL[32 * 264];  // [b][k 0..255], pad 264
    __shared__ u16 cL[32 * 264];
    const int d = blockIdx.x >> 1;
    const int half = blockIdx.x & 1;
    const int tid = threadIdx.x;
    const int w = tid >> 6;       // 0..7
    const int lane = tid & 63;
    const int l15 = lane & 15;
    const int quad = lane >> 4;
    const int jl = w * 16 + l15;          // col within own half (0..127)
    const int j = half * 128 + jl;        // global hidden col
    const float bdec = bd[j];

    // B fragments, REMAPPED for compile-time indexing:
    //   Bf[g][i] holds k-slice q = (half*4 + i) & 7  -> i=0..3 local, i=4..7 remote.
    short8 Bf[5][8];
#pragma unroll
    for (int g = 0; g < 5; ++g)
#pragma unroll
        for (int i = 0; i < 8; ++i) {
            const int q = (half * 4 + i) & 7;
            Bf[g][i] = *(const short8*)(U4t + (g << 16) + (j << 8) + (q << 5) + (quad << 3));
        }

    float creg[2][4], hreg[2][4];
#pragma unroll
    for (int mt = 0; mt < 2; ++mt)
#pragma unroll
        for (int r = 0; r < 4; ++r) { creg[mt][r] = 0.f; hreg[mt][r] = 0.f; }

    bool dead = false;
    const int q0 = half * 4;              // own-half k base (LDS addressing only)
    const int rq0 = 4 - half * 4;         // peer-half k base (LDS addressing only)
    const int rcol0 = 128 - half * 128;   // peer-half global col base

    for (int s = 0; s < SLEN; ++s) {
        const int sf = d ? (SLEN - 1 - s) : s;              // G source row
        const int tt = d ? (s == 0 ? 0 : SLEN - s) : s;     // tb = [t0, t511..t1]

        // ---- issue 8 peer loads FIRST: MALL latency hides under G prefetch ----
        u64 vals[8];
        const u32 want = (u32)(s - 1);
        // peer's buffer: [d][par][producer_half = 1-half], 4096 u64 each
        const u64* pr = exch + ((size_t)((((d << 1) | ((s - 1) & 1)) << 1) | (1 - half)) << 12);
        if (s > 0) {
#pragma unroll
            for (int k = 0; k < 8; ++k)
                vals[k] = __hip_atomic_load(&pr[(k << 9) | tid], __ATOMIC_RELAXED,
                                            __HIP_MEMORY_SCOPE_AGENT);
        }

        // ---- G preacts -> acc init, T (independent of exchange) ----
        float4v acc[5][2];
#pragma unroll
        for (int g = 0; g < 4; ++g)
#pragma unroll
            for (int mt = 0; mt < 2; ++mt) {
                const u16* Gp = G + (size_t)((mt * 16 + quad * 4) * SLEN + sf) * NDIM + g * 256 + j;
                float4v a;
#pragma unroll
                for (int r = 0; r < 4; ++r) a[r] = bf2f(Gp[(size_t)r * SLEN * NDIM]);
                acc[g][mt] = a;
            }
        float Tv[2][4];
#pragma unroll
        for (int mt = 0; mt < 2; ++mt)
#pragma unroll
            for (int r = 0; r < 4; ++r) {
                const int b = mt * 16 + quad * 4 + r;
                Tv[mt][r] = 1.f / logf(times[b * SLEN + tt] + 2.718281828459045f);
            }
#pragma unroll
        for (int mt = 0; mt < 2; ++mt) acc[4][mt] = (float4v)(bdec);

        if (s > 0) {
            // ---- local-half MFMAs (own 128 k-cols, staged via LDS last step) ----
            {
                short8 Ah[2][4], Ac[2][4];
#pragma unroll
                for (int mt = 0; mt < 2; ++mt)
#pragma unroll
                    for (int ql = 0; ql < 4; ++ql) {
                        const int off = (mt * 16 + l15) * 264 + (q0 + ql) * 32 + quad * 8;
                        Ah[mt][ql] = *(const short8*)(hL + off);
                        Ac[mt][ql] = *(const short8*)(cL + off);
                    }
#pragma unroll
                for (int ql = 0; ql < 4; ++ql)
#pragma unroll
                    for (int mt = 0; mt < 2; ++mt) {
                        acc[0][mt] = __builtin_amdgcn_mfma_f32_16x16x32_bf16(Ah[mt][ql], Bf[0][ql], acc[0][mt], 0, 0, 0);
                        acc[1][mt] = __builtin_amdgcn_mfma_f32_16x16x32_bf16(Ah[mt][ql], Bf[1][ql], acc[1][mt], 0, 0, 0);
                        acc[2][mt] = __builtin_amdgcn_mfma_f32_16x16x32_bf16(Ah[mt][ql], Bf[2][ql], acc[2][mt], 0, 0, 0);
                        acc[3][mt] = __builtin_amdgcn_mfma_f32_16x16x32_bf16(Ah[mt][ql], Bf[3][ql], acc[3][mt], 0, 0, 0);
                        acc[4][mt] = __builtin_amdgcn_mfma_f32_16x16x32_bf16(Ac[mt][ql], Bf[4][ql], acc[4][mt], 0, 0, 0);
                    }
            }
            // ---- peer poll: check tags; BULK re-read on miss (bounded, sticky) ----
            if (!dead) {
                u32 it = 0;
                for (;;) {
                    int ok = 1;
#pragma unroll
                    for (int k = 0; k < 8; ++k) ok &= ((u32)vals[k] == want);
                    if (__all(ok)) break;
                    if (++it > POLL_MAX) { dead = true; break; }  // finite, visible
#pragma unroll
                    for (int k = 0; k < 8; ++k)
                        vals[k] = __hip_atomic_load(&pr[(k << 9) | tid], __ATOMIC_RELAXED,
                                                    __HIP_MEMORY_SCOPE_AGENT);
                }
            }
            // ---- unpack peer -> LDS remote half ----
            const int rcol = rcol0 + (tid & 127);
            const int rb0 = tid >> 7;  // 0..3
#pragma unroll
            for (int k = 0; k < 8; ++k) {
                const int b = (k << 2) | rb0;
                const u32 hi = (u32)(vals[k] >> 32);
                hL[b * 264 + rcol] = (u16)(hi & 0xffffu);
                cL[b * 264 + rcol] = (u16)(hi >> 16);
            }
        }
        __syncthreads();  // B1: remote half staged; own-half reads (above) complete

        if (s > 0) {
            // ---- remote-half MFMAs (Bf[ .. ][4..7] -- literal indices) ----
            short8 Ah[2][4], Ac[2][4];
#pragma unroll
            for (int mt = 0; mt < 2; ++mt)
#pragma unroll
                for (int ql = 0; ql < 4; ++ql) {
                    const int off = (mt * 16 + l15) * 264 + (rq0 + ql) * 32 + quad * 8;
                    Ah[mt][ql] = *(const short8*)(hL + off);
                    Ac[mt][ql] = *(const short8*)(cL + off);
                }
#pragma unroll
            for (int ql = 0; ql < 4; ++ql)
#pragma unroll
                for (int mt = 0; mt < 2; ++mt) {
                    acc[0][mt] = __builtin_amdgcn_mfma_f32_16x16x32_bf16(Ah[mt][ql], Bf[0][4 + ql], acc[0][mt], 0, 0, 0);
                    acc[1][mt] = __builtin_amdgcn_mfma_f32_16x16x32_bf16(Ah[mt][ql], Bf[1][4 + ql], acc[1][mt], 0, 0, 0);
                    acc[2][mt] = __builtin_amdgcn_mfma_f32_16x16x32_bf16(Ah[mt][ql], Bf[2][4 + ql], acc[2][mt], 0, 0, 0);
                    acc[3][mt] = __builtin_amdgcn_mfma_f32_16x16x32_bf16(Ah[mt][ql], Bf[3][4 + ql], acc[3][mt], 0, 0, 0);
                    acc[4][mt] = __builtin_amdgcn_mfma_f32_16x16x32_bf16(Ac[mt][ql], Bf[4][4 + ql], acc[4][mt], 0, 0, 0);
                }
        }

        // ---- epilogue: gates; publish peer entries FIRST, then LDS, then out ----
        u64* pw = exch + ((size_t)((((d << 1) | (s & 1)) << 1) | half) << 12);
        float hv[2][4];
#pragma unroll
        for (int mt = 0; mt < 2; ++mt)
#pragma unroll
            for (int r = 0; r < 4; ++r) {
                const int b = mt * 16 + quad * 4 + r;
                const float C_ST = tanh_f(acc[4][mt][r]);
                const float cs = creg[mt][r] - C_ST + Tv[mt][r] * C_ST;
                const float ig = sigm(acc[0][mt][r]);
                const float fg = sigm(acc[1][mt][r]);
                const float og = sigm(acc[2][mt][r]);
                const float Cc = sigm(acc[3][mt][r]);
                const float cn = fg * cs + ig * Cc;
                const float hn = og * tanh_f(cn);
                creg[mt][r] = cn;
                hreg[mt][r] = hn;
                hv[mt][r] = hn;
                const u32 payload = ((u32)f2bf(cn) << 16) | (u32)f2bf(hn);
                const u64 v = ((u64)payload << 32) | (u64)(u32)s;
                __hip_atomic_store(&pw[(b << 7) | jl], v, __ATOMIC_RELAXED,
                                   __HIP_MEMORY_SCOPE_AGENT);
            }
        // own half -> LDS for next step's local phase (same f2bf rounding as peer path)
#pragma unroll
        for (int mt = 0; mt < 2; ++mt)
#pragma unroll
            for (int r = 0; r < 4; ++r) {
                const int b = mt * 16 + quad * 4 + r;
                hL[b * 264 + j] = f2bf(hreg[mt][r]);
                cL[b * 264 + j] = f2bf(creg[mt][r]);
            }
#pragma unroll
        for (int mt = 0; mt < 2; ++mt)
#pragma unroll
            for (int r = 0; r < 4; ++r) {
                const int b = mt * 16 + quad * 4 + r;
                out[((size_t)b * SLEN + s) * 512 + d * 256 + j] = hv[mt][r];
            }
        __syncthreads();  // B2: LDS writes visible before next step's local reads
    }

    // h_last, c_last
    const size_t base2 = (size_t)BATCH * SLEN * 512;
#pragma unroll
    for (int mt = 0; mt < 2; ++mt)
#pragma unroll
        for (int r = 0; r < 4; ++r) {
            const int b = mt * 16 + quad * 4 + r;
            out[base2 + b * 512 + d * 256 + j] = hreg[mt][r];
            out[base2 + BATCH * 512 + b * 512 + d * 256 + j] = creg[mt][r];
        }
}

extern "C" void kernel_launch(void* const* d_in, const int* in_sizes, int n_in,
                              void* d_out, int out_size, void* d_ws, size_t ws_size,
                              hipStream_t stream) {
    const float* inputs = (const float*)d_in[0];
    const float* times = (const float*)d_in[1];
    WPtrs p;
    p.Wi = (const float*)d_in[2];  p.Ui = (const float*)d_in[3];  p.bi = (const float*)d_in[4];
    p.Wf = (const float*)d_in[5];  p.Uf = (const float*)d_in[6];  p.bfp = (const float*)d_in[7];
    p.Wog = (const float*)d_in[8]; p.Uog = (const float*)d_in[9]; p.bog = (const float*)d_in[10];
    p.Wc = (const float*)d_in[11]; p.Uc = (const float*)d_in[12]; p.bc = (const float*)d_in[13];
    p.Wd = (const float*)d_in[14]; p.bd = (const float*)d_in[15];

    char* ws = (char*)d_ws;
    u16* W4t = (u16*)ws;                   // 1024*768*2   = 1,572,864 B (gemm phase only)
    u16* U4t = (u16*)(ws + 1572864);       // 5*256*256*2  =   655,360 B
    float* b4 = (float*)(ws + 2228224);    // 1024*4       =     4,096 B
    u16* G = (u16*)(ws + 2232320);         // 16384*1024*2 = 33,554,432 B
    // recur-phase exchange aliases the (dead) W4t region:
    // [2 dir][2 par][2 producer-half][32 b][128 col] u64 tagged entries = 262,144 B
    u64* exch = (u64*)ws;

    hipLaunchKernelGGL(convert_kernel, dim3(1024), dim3(256), 0, stream, p, W4t, U4t, b4);
    hipLaunchKernelGGL(gemm_g_kernel, dim3(8, 128), dim3(256), 0, stream, inputs, W4t, b4, G);
    hipMemsetAsync(ws, 0xFF, 262144, stream);  // tags -> 0xFFFFFFFF (never a valid step)
    hipLaunchKernelGGL(recur_mfma_kernel, dim3(4), dim3(512), 0, stream, times, p.bd, U4t, G,
                       exch, (float*)d_out);
}

// Round 9
// 5190.471 us; speedup vs baseline: 1.6507x; 1.0138x over previous
//
#include <hip/hip_runtime.h>
#include <math.h>

#define SLEN 512
#define BATCH 32
#define IDIM 768
#define HDIM 256
#define NDIM 1024  // 4*HDIM
#define POLL_MAX (1u << 16)

typedef unsigned short u16;
typedef unsigned int u32;
typedef unsigned long long u64;
typedef __attribute__((ext_vector_type(8))) short short8;     // 8 bf16 (MFMA A/B frag)
typedef __attribute__((ext_vector_type(4))) float float4v;    // MFMA C/D frag
typedef __attribute__((ext_vector_type(4))) unsigned short ushort4v;
typedef __attribute__((ext_vector_type(4))) unsigned int uint4v;

__device__ __forceinline__ float bf2f(u16 v) {
    union { u32 u; float f; } c; c.u = ((u32)v) << 16; return c.f;
}
__device__ __forceinline__ u16 f2bf(float f) {
    union { float f; u32 u; } c; c.f = f;
    u32 u = c.u;
    return (u16)((u + 0x7fffu + ((u >> 16) & 1u)) >> 16);
}
__device__ __forceinline__ float sigm(float x) { return 1.f / (1.f + __expf(-x)); }
__device__ __forceinline__ float tanh_f(float x) { return 1.f - 2.f / (__expf(2.f * x) + 1.f); }

struct WPtrs {
    const float *Wi, *Ui, *bi, *Wf, *Uf, *bfp, *Wog, *Uog, *bog, *Wc, *Uc, *bc, *Wd, *bd;
};

// ---------------- kernel 0: weight conversion ----------------
// W4t: bf16 [1024 n][768 k]  (transposed concat Wi,Wf,Wog,Wc) for GEMM B-frags
// U4t: bf16 [5 mat][256 n][256 k]  (transposed: i,f,o,c,Wd) for recurrence B-frags
// b4 : fp32 [1024] concat gate biases
__global__ void convert_kernel(WPtrs p, u16* __restrict__ W4t, u16* __restrict__ U4t,
                               float* __restrict__ b4) {
    const float* Wg[4] = {p.Wi, p.Wf, p.Wog, p.Wc};
    const float* Ug[4] = {p.Ui, p.Uf, p.Uog, p.Uc};
    const float* bg[4] = {p.bi, p.bfp, p.bog, p.bc};
    const int total = NDIM * IDIM + 5 * HDIM * HDIM + NDIM;
    for (int idx = blockIdx.x * blockDim.x + threadIdx.x; idx < total;
         idx += gridDim.x * blockDim.x) {
        int i = idx;
        if (i < NDIM * IDIM) {
            int n = i / IDIM, k = i - n * IDIM;
            W4t[i] = f2bf(Wg[n >> 8][k * HDIM + (n & 255)]);
        } else if ((i -= NDIM * IDIM) < 5 * HDIM * HDIM) {
            int g = i >> 16, rem = i & 65535, n = rem >> 8, k = rem & 255;
            const float* M = (g < 4) ? Ug[g] : p.Wd;
            U4t[i] = f2bf(M[k * HDIM + n]);
        } else {
            i -= 5 * HDIM * HDIM;
            b4[i] = bg[i >> 8][i & 255];
        }
    }
}

// ---------------- kernel 1: G = x @ W4 + b4  (bf16 MFMA, 128x128 tiles) ----------------
__global__ __launch_bounds__(256) void gemm_g_kernel(const float* __restrict__ x,
                                                     const u16* __restrict__ W4t,
                                                     const float* __restrict__ b4,
                                                     u16* __restrict__ G) {
    __shared__ u16 As[128][40];
    __shared__ u16 Bs[128][40];
    const int bn = blockIdx.x;   // 0..7
    const int bm = blockIdx.y;   // 0..127
    const int tid = threadIdx.x;
    const int w = tid >> 6, lane = tid & 63;
    const int wr = w >> 1, wc = w & 1;
    const int l15 = lane & 15, quad = lane >> 4;
    const int m0 = bm * 128, n0 = bn * 128;

    float4v acc[4][4];
#pragma unroll
    for (int a = 0; a < 4; ++a)
#pragma unroll
        for (int b = 0; b < 4; ++b) acc[a][b] = (float4v)(0.f);

    for (int kt = 0; kt < IDIM / 32; ++kt) {
        const int k0 = kt * 32;
#pragma unroll
        for (int i = 0; i < 4; ++i) {
            int idx = tid + 256 * i;
            int r = idx >> 3, seg = idx & 7;
            float4v xv = *(const float4v*)(x + (size_t)(m0 + r) * IDIM + k0 + seg * 4);
            ushort4v t;
            t.x = f2bf(xv.x); t.y = f2bf(xv.y); t.z = f2bf(xv.z); t.w = f2bf(xv.w);
            *(ushort4v*)(&As[r][seg * 4]) = t;
        }
#pragma unroll
        for (int i = 0; i < 2; ++i) {
            int idx = tid + 256 * i;
            int r = idx >> 2, seg = idx & 3;
            uint4v bv = *(const uint4v*)(W4t + (size_t)(n0 + r) * IDIM + k0 + seg * 8);
            *(uint4v*)(&Bs[r][seg * 8]) = bv;
        }
        __syncthreads();
        short8 afr[4], bfr[4];
#pragma unroll
        for (int mt = 0; mt < 4; ++mt) {
            int row = wr * 64 + mt * 16 + l15;
            afr[mt] = *(const short8*)(&As[row][quad * 8]);
        }
#pragma unroll
        for (int nt = 0; nt < 4; ++nt) {
            int col = wc * 64 + nt * 16 + l15;
            bfr[nt] = *(const short8*)(&Bs[col][quad * 8]);
        }
#pragma unroll
        for (int mt = 0; mt < 4; ++mt)
#pragma unroll
            for (int nt = 0; nt < 4; ++nt)
                acc[mt][nt] = __builtin_amdgcn_mfma_f32_16x16x32_bf16(afr[mt], bfr[nt],
                                                                      acc[mt][nt], 0, 0, 0);
        __syncthreads();
    }
#pragma unroll
    for (int mt = 0; mt < 4; ++mt)
#pragma unroll
        for (int nt = 0; nt < 4; ++nt) {
            int gm = m0 + wr * 64 + mt * 16 + quad * 4;
            int gn = n0 + wc * 64 + nt * 16 + l15;
            float bias = b4[gn];
#pragma unroll
            for (int r = 0; r < 4; ++r) {
                G[(size_t)(gm + r) * NDIM + gn] = f2bf(acc[mt][nt][r] + bias);
            }
        }
}

// ---------------- kernel 2: recurrence (MFMA, half-split, peer exchange) -----------
// 4 blocks = 2 dirs x 2 halves(128 cols). 512 threads = 8 waves; wave w owns cols
// [half*128 + w*16, +16); B-frags in VGPRs for all 512 steps.
// Round-7 post-mortem fix: __launch_bounds__(512,2) was applied as CUDA-semantics
// "min 2 BLOCKS/CU" = 16 waves/CU = 4 waves/SIMD -> 128-VGPR cap (VGPR_Count=128
// exactly), so Bf[5][8] (160 VGPRs) could never be resident -> rematerialized every
// step (~7us/step). Now (512,1): cap >=256 under either semantics; we launch only
// 4 blocks on 256 CUs so 1-block/CU residency costs nothing.
// Bf[g][i] holds k-slice q=(half*4+i)&7 -> local phase Bf[g][0..3], remote phase
// Bf[g][4..7] -- all literal register indices (rule #20); LDS addresses keep the
// runtime q0/rq0. Exchange (round-0-proven): u64 = {c,h bf16}<<32 | step; tag rides
// with payload, fire-and-forget agent-scope relaxed atomics, compiler-managed. Peer
// loads issued BEFORE the G prefetch; checked AFTER local-half MFMAs; bulk re-poll;
// bounded + sticky dead (finite visible error, never a hang).
__global__ __launch_bounds__(512, 1) void recur_mfma_kernel(
    const float* __restrict__ times, const float* __restrict__ bd,
    const u16* __restrict__ U4t, const u16* __restrict__ G,
    u64* __restrict__ exch, float* __restrict__ out) {
    __shared__ u16 hL[32 * 264];  // [b][k 0..255], pad 264
    __shared__ u16 cL[32 * 264];
    const int d = blockIdx.x >> 1;
    const int half = blockIdx.x & 1;
    const int tid = threadIdx.x;
    const int w = tid >> 6;       // 0..7
    const int lane = tid & 63;
    const int l15 = lane & 15;
    const int quad = lane >> 4;
    const int jl = w * 16 + l15;          // col within own half (0..127)
    const int j = half * 128 + jl;        // global hidden col
    const float bdec = bd[j];

    // B fragments, REMAPPED for compile-time indexing:
    //   Bf[g][i] holds k-slice q = (half*4 + i) & 7  -> i=0..3 local, i=4..7 remote.
    short8 Bf[5][8];
#pragma unroll
    for (int g = 0; g < 5; ++g)
#pragma unroll
        for (int i = 0; i < 8; ++i) {
            const int q = (half * 4 + i) & 7;
            Bf[g][i] = *(const short8*)(U4t + (g << 16) + (j << 8) + (q << 5) + (quad << 3));
        }

    float creg[2][4], hreg[2][4];
#pragma unroll
    for (int mt = 0; mt < 2; ++mt)
#pragma unroll
        for (int r = 0; r < 4; ++r) { creg[mt][r] = 0.f; hreg[mt][r] = 0.f; }

    bool dead = false;
    const int q0 = half * 4;              // own-half k base (LDS addressing only)
    const int rq0 = 4 - half * 4;         // peer-half k base (LDS addressing only)
    const int rcol0 = 128 - half * 128;   // peer-half global col base

    for (int s = 0; s < SLEN; ++s) {
        const int sf = d ? (SLEN - 1 - s) : s;              // G source row
        const int tt = d ? (s == 0 ? 0 : SLEN - s) : s;     // tb = [t0, t511..t1]

        // ---- issue 8 peer loads FIRST: MALL latency hides under G prefetch ----
        u64 vals[8];
        const u32 want = (u32)(s - 1);
        // peer's buffer: [d][par][producer_half = 1-half], 4096 u64 each
        const u64* pr = exch + ((size_t)((((d << 1) | ((s - 1) & 1)) << 1) | (1 - half)) << 12);
        if (s > 0) {
#pragma unroll
            for (int k = 0; k < 8; ++k)
                vals[k] = __hip_atomic_load(&pr[(k << 9) | tid], __ATOMIC_RELAXED,
                                            __HIP_MEMORY_SCOPE_AGENT);
        }

        // ---- G preacts -> acc init, T (independent of exchange) ----
        float4v acc[5][2];
#pragma unroll
        for (int g = 0; g < 4; ++g)
#pragma unroll
            for (int mt = 0; mt < 2; ++mt) {
                const u16* Gp = G + (size_t)((mt * 16 + quad * 4) * SLEN + sf) * NDIM + g * 256 + j;
                float4v a;
#pragma unroll
                for (int r = 0; r < 4; ++r) a[r] = bf2f(Gp[(size_t)r * SLEN * NDIM]);
                acc[g][mt] = a;
            }
        float Tv[2][4];
#pragma unroll
        for (int mt = 0; mt < 2; ++mt)
#pragma unroll
            for (int r = 0; r < 4; ++r) {
                const int b = mt * 16 + quad * 4 + r;
                Tv[mt][r] = 1.f / logf(times[b * SLEN + tt] + 2.718281828459045f);
            }
#pragma unroll
        for (int mt = 0; mt < 2; ++mt) acc[4][mt] = (float4v)(bdec);

        if (s > 0) {
            // ---- local-half MFMAs (own 128 k-cols, staged via LDS last step) ----
            {
                short8 Ah[2][4], Ac[2][4];
#pragma unroll
                for (int mt = 0; mt < 2; ++mt)
#pragma unroll
                    for (int ql = 0; ql < 4; ++ql) {
                        const int off = (mt * 16 + l15) * 264 + (q0 + ql) * 32 + quad * 8;
                        Ah[mt][ql] = *(const short8*)(hL + off);
                        Ac[mt][ql] = *(const short8*)(cL + off);
                    }
#pragma unroll
                for (int ql = 0; ql < 4; ++ql)
#pragma unroll
                    for (int mt = 0; mt < 2; ++mt) {
                        acc[0][mt] = __builtin_amdgcn_mfma_f32_16x16x32_bf16(Ah[mt][ql], Bf[0][ql], acc[0][mt], 0, 0, 0);
                        acc[1][mt] = __builtin_amdgcn_mfma_f32_16x16x32_bf16(Ah[mt][ql], Bf[1][ql], acc[1][mt], 0, 0, 0);
                        acc[2][mt] = __builtin_amdgcn_mfma_f32_16x16x32_bf16(Ah[mt][ql], Bf[2][ql], acc[2][mt], 0, 0, 0);
                        acc[3][mt] = __builtin_amdgcn_mfma_f32_16x16x32_bf16(Ah[mt][ql], Bf[3][ql], acc[3][mt], 0, 0, 0);
                        acc[4][mt] = __builtin_amdgcn_mfma_f32_16x16x32_bf16(Ac[mt][ql], Bf[4][ql], acc[4][mt], 0, 0, 0);
                    }
            }
            // ---- peer poll: check tags; BULK re-read on miss (bounded, sticky) ----
            if (!dead) {
                u32 it = 0;
                for (;;) {
                    int ok = 1;
#pragma unroll
                    for (int k = 0; k < 8; ++k) ok &= ((u32)vals[k] == want);
                    if (__all(ok)) break;
                    if (++it > POLL_MAX) { dead = true; break; }  // finite, visible
#pragma unroll
                    for (int k = 0; k < 8; ++k)
                        vals[k] = __hip_atomic_load(&pr[(k << 9) | tid], __ATOMIC_RELAXED,
                                                    __HIP_MEMORY_SCOPE_AGENT);
                }
            }
            // ---- unpack peer -> LDS remote half ----
            const int rcol = rcol0 + (tid & 127);
            const int rb0 = tid >> 7;  // 0..3
#pragma unroll
            for (int k = 0; k < 8; ++k) {
                const int b = (k << 2) | rb0;
                const u32 hi = (u32)(vals[k] >> 32);
                hL[b * 264 + rcol] = (u16)(hi & 0xffffu);
                cL[b * 264 + rcol] = (u16)(hi >> 16);
            }
        }
        __syncthreads();  // B1: remote half staged; own-half reads (above) complete

        if (s > 0) {
            // ---- remote-half MFMAs (Bf[ .. ][4..7] -- literal indices) ----
            short8 Ah[2][4], Ac[2][4];
#pragma unroll
            for (int mt = 0; mt < 2; ++mt)
#pragma unroll
                for (int ql = 0; ql < 4; ++ql) {
                    const int off = (mt * 16 + l15) * 264 + (rq0 + ql) * 32 + quad * 8;
                    Ah[mt][ql] = *(const short8*)(hL + off);
                    Ac[mt][ql] = *(const short8*)(cL + off);
                }
#pragma unroll
            for (int ql = 0; ql < 4; ++ql)
#pragma unroll
                for (int mt = 0; mt < 2; ++mt) {
                    acc[0][mt] = __builtin_amdgcn_mfma_f32_16x16x32_bf16(Ah[mt][ql], Bf[0][4 + ql], acc[0][mt], 0, 0, 0);
                    acc[1][mt] = __builtin_amdgcn_mfma_f32_16x16x32_bf16(Ah[mt][ql], Bf[1][4 + ql], acc[1][mt], 0, 0, 0);
                    acc[2][mt] = __builtin_amdgcn_mfma_f32_16x16x32_bf16(Ah[mt][ql], Bf[2][4 + ql], acc[2][mt], 0, 0, 0);
                    acc[3][mt] = __builtin_amdgcn_mfma_f32_16x16x32_bf16(Ah[mt][ql], Bf[3][4 + ql], acc[3][mt], 0, 0, 0);
                    acc[4][mt] = __builtin_amdgcn_mfma_f32_16x16x32_bf16(Ac[mt][ql], Bf[4][4 + ql], acc[4][mt], 0, 0, 0);
                }
        }

        // ---- epilogue: gates; publish peer entries FIRST, then LDS, then out ----
        u64* pw = exch + ((size_t)((((d << 1) | (s & 1)) << 1) | half) << 12);
        float hv[2][4];
#pragma unroll
        for (int mt = 0; mt < 2; ++mt)
#pragma unroll
            for (int r = 0; r < 4; ++r) {
                const int b = mt * 16 + quad * 4 + r;
                const float C_ST = tanh_f(acc[4][mt][r]);
                const float cs = creg[mt][r] - C_ST + Tv[mt][r] * C_ST;
                const float ig = sigm(acc[0][mt][r]);
                const float fg = sigm(acc[1][mt][r]);
                const float og = sigm(acc[2][mt][r]);
                const float Cc = sigm(acc[3][mt][r]);
                const float cn = fg * cs + ig * Cc;
                const float hn = og * tanh_f(cn);
                creg[mt][r] = cn;
                hreg[mt][r] = hn;
                hv[mt][r] = hn;
                const u32 payload = ((u32)f2bf(cn) << 16) | (u32)f2bf(hn);
                const u64 v = ((u64)payload << 32) | (u64)(u32)s;
                __hip_atomic_store(&pw[(b << 7) | jl], v, __ATOMIC_RELAXED,
                                   __HIP_MEMORY_SCOPE_AGENT);
            }
        // own half -> LDS for next step's local phase (same f2bf rounding as peer path)
#pragma unroll
        for (int mt = 0; mt < 2; ++mt)
#pragma unroll
            for (int r = 0; r < 4; ++r) {
                const int b = mt * 16 + quad * 4 + r;
                hL[b * 264 + j] = f2bf(hreg[mt][r]);
                cL[b * 264 + j] = f2bf(creg[mt][r]);
            }
#pragma unroll
        for (int mt = 0; mt < 2; ++mt)
#pragma unroll
            for (int r = 0; r < 4; ++r) {
                const int b = mt * 16 + quad * 4 + r;
                out[((size_t)b * SLEN + s) * 512 + d * 256 + j] = hv[mt][r];
            }
        __syncthreads();  // B2: LDS writes visible before next step's local reads
    }

    // h_last, c_last
    const size_t base2 = (size_t)BATCH * SLEN * 512;
#pragma unroll
    for (int mt = 0; mt < 2; ++mt)
#pragma unroll
        for (int r = 0; r < 4; ++r) {
            const int b = mt * 16 + quad * 4 + r;
            out[base2 + b * 512 + d * 256 + j] = hreg[mt][r];
            out[base2 + BATCH * 512 + b * 512 + d * 256 + j] = creg[mt][r];
        }
}

extern "C" void kernel_launch(void* const* d_in, const int* in_sizes, int n_in,
                              void* d_out, int out_size, void* d_ws, size_t ws_size,
                              hipStream_t stream) {
    const float* inputs = (const float*)d_in[0];
    const float* times = (const float*)d_in[1];
    WPtrs p;
    p.Wi = (const float*)d_in[2];  p.Ui = (const float*)d_in[3];  p.bi = (const float*)d_in[4];
    p.Wf = (const float*)d_in[5];  p.Uf = (const float*)d_in[6];  p.bfp = (const float*)d_in[7];
    p.Wog = (const float*)d_in[8]; p.Uog = (const float*)d_in[9]; p.bog = (const float*)d_in[10];
    p.Wc = (const float*)d_in[11]; p.Uc = (const float*)d_in[12]; p.bc = (const float*)d_in[13];
    p.Wd = (const float*)d_in[14]; p.bd = (const float*)d_in[15];

    char* ws = (char*)d_ws;
    u16* W4t = (u16*)ws;                   // 1024*768*2   = 1,572,864 B (gemm phase only)
    u16* U4t = (u16*)(ws + 1572864);       // 5*256*256*2  =   655,360 B
    float* b4 = (float*)(ws + 2228224);    // 1024*4       =     4,096 B
    u16* G = (u16*)(ws + 2232320);         // 16384*1024*2 = 33,554,432 B
    // recur-phase exchange aliases the (dead) W4t region:
    // [2 dir][2 par][2 producer-half][32 b][128 col] u64 tagged entries = 262,144 B
    u64* exch = (u64*)ws;

    hipLaunchKernelGGL(convert_kernel, dim3(1024), dim3(256), 0, stream, p, W4t, U4t, b4);
    hipLaunchKernelGGL(gemm_g_kernel, dim3(8, 128), dim3(256), 0, stream, inputs, W4t, b4, G);
    hipMemsetAsync(ws, 0xFF, 262144, stream);  // tags -> 0xFFFFFFFF (never a valid step)
    hipLaunchKernelGGL(recur_mfma_kernel, dim3(4), dim3(512), 0, stream, times, p.bd, U4t, G,
                       exch, (float*)d_out);
}